// Round 8
// baseline (8321.769 us; speedup 1.0000x reference)
//
#include <hip/hip_runtime.h>
#include <hip/hip_bf16.h>

using bf16 = __hip_bfloat16;
typedef __attribute__((ext_vector_type(8))) short short8;
typedef __attribute__((ext_vector_type(4))) float f32x4;

static __device__ __forceinline__ float b2f(unsigned short s) {
    unsigned u = ((unsigned)s) << 16;
    return __builtin_bit_cast(float, u);
}
static __device__ __forceinline__ short f2b(float f) {
    __hip_bfloat16 h = __float2bfloat16(f);
    return __builtin_bit_cast(short, h);
}
static __device__ __forceinline__ void load_lds16(const void* g, void* l) {
    __builtin_amdgcn_global_load_lds(
        (const __attribute__((address_space(1))) void*)g,
        (__attribute__((address_space(3))) void*)l, 16, 0, 0);
}
static __device__ __forceinline__ void load_lds4(const void* g, void* l) {
    __builtin_amdgcn_global_load_lds(
        (const __attribute__((address_space(1))) void*)g,
        (__attribute__((address_space(3))) void*)l, 4, 0, 0);
}

// ---------------- f32 -> bf16 conversion (8 elems/thread) ----------------
__global__ void f32_to_bf16_vec(const float* __restrict__ in, bf16* __restrict__ out, int n8) {
    int i = blockIdx.x * blockDim.x + threadIdx.x;
    if (i >= n8) return;
    const f32x4* p = (const f32x4*)(in + (size_t)i * 8);
    f32x4 a = p[0], b = p[1];
    short8 o;
    o[0] = f2b(a[0]); o[1] = f2b(a[1]); o[2] = f2b(a[2]); o[3] = f2b(a[3]);
    o[4] = f2b(b[0]); o[5] = f2b(b[1]); o[6] = f2b(b[2]); o[7] = f2b(b[3]);
    *(short8*)(out + (size_t)i * 8) = o;
}

// ---------------- GEMM: C = act(X @ W^T + bias), bf16 in/out ----------------
template<int K, bool RELU>
__global__ __launch_bounds__(256) void gemm_xwt(
    const bf16* __restrict__ X, const bf16* __restrict__ W,
    const float* __restrict__ bias, bf16* __restrict__ C, int Nout)
{
    __shared__ bf16 As[128][40];
    __shared__ bf16 Bs[128][40];
    const int tid  = threadIdx.x;
    const int wave = tid >> 6, lane = tid & 63;
    const int wr = wave >> 1, wc = wave & 1;
    const long Mbase = (long)blockIdx.x * 128;
    const int  Nbase = blockIdx.y * 128;
    const int kg = (lane >> 4) * 8;

    f32x4 acc[4][4];
#pragma unroll
    for (int i = 0; i < 4; ++i)
#pragma unroll
        for (int j = 0; j < 4; ++j) acc[i][j] = (f32x4){0.f, 0.f, 0.f, 0.f};

    for (int kb = 0; kb < K / 32; ++kb) {
        __syncthreads();
#pragma unroll
        for (int q = 0; q < 2; ++q) {
            int idx = q * 256 + tid;
            int row = idx >> 2, kp = (idx & 3) * 8;
            *(short8*)&As[row][kp] = *(const short8*)&X[(Mbase + row) * K + kb * 32 + kp];
            *(short8*)&Bs[row][kp] = *(const short8*)&W[(long)(Nbase + row) * K + kb * 32 + kp];
        }
        __syncthreads();
        short8 a[4], b[4];
#pragma unroll
        for (int mt = 0; mt < 4; ++mt)
            a[mt] = *(const short8*)&As[wr * 64 + mt * 16 + (lane & 15)][kg];
#pragma unroll
        for (int nt = 0; nt < 4; ++nt)
            b[nt] = *(const short8*)&Bs[wc * 64 + nt * 16 + (lane & 15)][kg];
#pragma unroll
        for (int mt = 0; mt < 4; ++mt)
#pragma unroll
            for (int nt = 0; nt < 4; ++nt)
                acc[mt][nt] = __builtin_amdgcn_mfma_f32_16x16x32_bf16(a[mt], b[nt], acc[mt][nt], 0, 0, 0);
    }

#pragma unroll
    for (int mt = 0; mt < 4; ++mt) {
        int row0 = wr * 64 + mt * 16 + (lane >> 4) * 4;
#pragma unroll
        for (int nt = 0; nt < 4; ++nt) {
            int col = Nbase + wc * 64 + nt * 16 + (lane & 15);
            float bv = bias[col];
#pragma unroll
            for (int r = 0; r < 4; ++r) {
                float v = acc[mt][nt][r] + bv;
                if (RELU) v = fmaxf(v, 0.f);
                C[(Mbase + row0 + r) * (long)Nout + col] = __float2bfloat16(v);
            }
        }
    }
}

// ---------------- LayerNorm rows of 512, bf16 -> bf16 ----------------
__global__ __launch_bounds__(256) void ln_rows512(
    const bf16* __restrict__ in, bf16* __restrict__ out,
    const float* __restrict__ g, const float* __restrict__ be)
{
    const int lane = threadIdx.x & 63;
    const long row = (long)blockIdx.x * 4 + (threadIdx.x >> 6);
    const bf16* rp = in + row * 512;
    short8 v = *(const short8*)&rp[lane * 8];
    float x[8]; float s = 0.f, sq = 0.f;
#pragma unroll
    for (int j = 0; j < 8; ++j) { x[j] = b2f((unsigned short)v[j]); s += x[j]; sq += x[j] * x[j]; }
#pragma unroll
    for (int m = 1; m < 64; m <<= 1) { s += __shfl_xor(s, m); sq += __shfl_xor(sq, m); }
    float mu   = s * (1.f / 512.f);
    float var  = sq * (1.f / 512.f) - mu * mu;
    float rstd = rsqrtf(var + 1e-5f);
    short8 o;
#pragma unroll
    for (int j = 0; j < 8; ++j) {
        int c = lane * 8 + j;
        o[j] = f2b((x[j] - mu) * rstd * g[c] + be[c]);
    }
    *(short8*)(out + row * 512 + lane * 8) = o;
}

// ---------------- GRU scan v8: DMA-pipelined Whh stream (3-buf, counted vmcnt) ------
// 16 blocks x 32 batch rows, 512 threads = 8 waves (rt=w>>2, ct=w&3).
// Step = 48 phases; phase (c,g,kh) stages the 32KB Whh tile [gate g, cols c*64..+64,
// K-half kh] via global_load_lds into a 3x32KB LDS ring, 2 stages in flight
// (vmcnt(10), 5 DMA/phase/thread: 4 Whh + 1 gi dword). Consume: XOR-swizzled
// ds_read_b128 + 8 MFMA into acc[g]. Gates fire after each col-group's 6th phase,
// fed from a DMA-staged gi double-buffer. h master f32 in regs; hb bf16 in LDS.
__global__ __launch_bounds__(512, 2) void gru_scan8(
    const bf16* __restrict__ gi, const float* __restrict__ on_reset,
    const float* __restrict__ hx, const bf16* __restrict__ Whh,
    const float* __restrict__ bhh, const float* __restrict__ gr,
    const float* __restrict__ br, float* __restrict__ out, float* __restrict__ hT)
{
    __shared__ char  Bst[3 * 32768];   // 96 KB Whh tile ring
    __shared__ bf16  hb[32][520];      // 33.25 KB pre-masked bf16 h
    __shared__ char  giS[2 * 12288];   // 24 KB gi double buffer [g][row][128B]
    __shared__ float lnS[32][4];       // LN partials [row][ct]
    __shared__ float lnQ[32][4];

    const int tid = threadIdx.x;
    const int w   = tid >> 6, lane = tid & 63;
    const int lc  = lane & 15, kg = lane >> 4;
    const int rt  = w >> 2, ct = w & 3;
    const int n0  = blockIdx.x * 32;
    const char* WhhB = (const char*)Whh;
    const char* giB  = (const char*)gi;

#define STAGE_W(np) do {                                                     \
        const int c_ = (np) / 6, rem_ = (np) % 6;                            \
        const int g_ = rem_ >> 1, kh_ = rem_ & 1;                            \
        const int R0_ = g_ * 512 + c_ * 64;                                  \
        char* db_ = Bst + ((np) % 3) * 32768;                                \
        _Pragma("unroll")                                                    \
        for (int j_ = 0; j_ < 4; ++j_) {                                     \
            const int idx_ = j_ * 512 + tid;                                 \
            const int row_ = idx_ >> 5, ib_ = idx_ & 31;                     \
            const char* s_ = WhhB + (((size_t)(R0_ + row_)) << 10)           \
                           + kh_ * 512 + ((ib_ << 4) ^ ((row_ & 7) << 4));   \
            load_lds16(s_, db_ + idx_ * 16);                                 \
        }                                                                    \
    } while (0)

#define STAGE_GI(tsrc, grp, chunk) do {                                      \
        const int slot_ = (chunk) * 512 + tid;                               \
        const int g_ = slot_ >> 10, rem_ = slot_ & 1023;                     \
        const int row_ = rem_ >> 5, o2_ = rem_ & 31;                         \
        const char* s_ = giB + (((size_t)(tsrc) * 512 + n0 + row_) * 1536    \
                               + g_ * 512 + (grp) * 64 + o2_ * 2) * 2;       \
        load_lds4(s_, giS + ((grp) & 1) * 12288 + slot_ * 4);                \
    } while (0)

    // ---- h master init (f32 regs) + hb(0) ----
    float hreg[8][4];   // [col-group][r]
#pragma unroll
    for (int r = 0; r < 4; ++r) {
        const int row = rt * 16 + kg * 4 + r;
        const float m0 = on_reset[n0 + row];
#pragma unroll
        for (int c = 0; c < 8; ++c) {
            const int col = c * 64 + ct * 16 + lc;
            float v = hx[(size_t)(n0 + row) * 512 + col];
            hreg[c][r] = v;
            hb[row][col] = __float2bfloat16(v * m0);
        }
    }
    // prologue: Whh phases 0,1 + gi(group 0 of t=0)
    STAGE_W(0);
    STAGE_W(1);
#pragma unroll
    for (int ch = 0; ch < 6; ++ch) STAGE_GI(0, 0, ch);
    __syncthreads();   // full drain once (prologue only)

#pragma unroll 1
    for (int t = 0; t < 128; ++t) {
        // A-frags (regs for whole step); masks
        short8 aF[16];
#pragma unroll
        for (int kc = 0; kc < 16; ++kc)
            aF[kc] = *(const short8*)&hb[rt * 16 + lc][kc * 32 + kg * 8];
        float mcur[4], mnx[4];
#pragma unroll
        for (int r = 0; r < 4; ++r) {
            const int row = rt * 16 + kg * 4 + r;
            mcur[r] = on_reset[(size_t)t * 512 + n0 + row];
            mnx[r]  = (t < 127) ? on_reset[(size_t)(t + 1) * 512 + n0 + row] : 1.f;
        }
        float sacc[4] = {0.f, 0.f, 0.f, 0.f}, qacc[4] = {0.f, 0.f, 0.f, 0.f};

#pragma unroll
        for (int c = 0; c < 8; ++c) {
            f32x4 acc[3];
#pragma unroll
            for (int g = 0; g < 3; ++g) acc[g] = (f32x4){0.f, 0.f, 0.f, 0.f};

#pragma unroll
            for (int g = 0; g < 3; ++g) {
#pragma unroll
                for (int kh = 0; kh < 2; ++kh) {
                    const int p = c * 6 + g * 2 + kh;
                    __builtin_amdgcn_s_barrier();
                    __builtin_amdgcn_sched_barrier(0);
                    // consume tile p
                    {
                        const char* bb = Bst + (p % 3) * 32768;
                        const int lrow = ct * 16 + lc;
#pragma unroll
                        for (int i = 0; i < 8; ++i) {
                            const int byo = (i * 64 + kg * 16) ^ ((lrow & 7) << 4);
                            short8 bq = *(const short8*)(bb + lrow * 512 + byo);
                            acc[g] = __builtin_amdgcn_mfma_f32_16x16x32_bf16(
                                aF[kh * 8 + i], bq, acc[g], 0, 0, 0);
                        }
                    }
                    if (g == 2 && kh == 1) {
                        // ---- gates for col-group c ----
                        const char* gB = giS + (c & 1) * 12288;
                        const int cig = ct * 16 + lc;
                        const int col = c * 64 + cig;
                        const float bhr = bhh[col];
                        const float bhz = bhh[512 + col];
                        const float bhn = bhh[1024 + col];
#pragma unroll
                        for (int r = 0; r < 4; ++r) {
                            const int row = rt * 16 + kg * 4 + r;
                            const float ir  = b2f(*(const unsigned short*)(gB + row * 128 + cig * 2));
                            const float iz  = b2f(*(const unsigned short*)(gB + 4096 + row * 128 + cig * 2));
                            const float inn = b2f(*(const unsigned short*)(gB + 8192 + row * 128 + cig * 2));
                            const float hr = acc[0][r] + bhr;
                            const float hz = acc[1][r] + bhz;
                            const float hn = acc[2][r] + bhn;
                            const float rg = 1.f / (1.f + __expf(-(ir + hr)));
                            const float zg = 1.f / (1.f + __expf(-(iz + hz)));
                            const float e2 = __expf(2.f * (inn + rg * hn));
                            const float ng = 1.f - 2.f / (e2 + 1.f);   // tanh
                            const float hv = (1.f - zg) * ng + zg * (hreg[c][r] * mcur[r]);
                            hreg[c][r] = hv;
                            hb[row][col] = __float2bfloat16(hv * mnx[r]);
                            sacc[r] += hv; qacc[r] += hv * hv;
                        }
                    }
                    // stage phase p+2 (Whh ring, wraps across steps for free) + gi chunk
                    STAGE_W((p + 2) % 48);
                    {
                        const int grp = (c + 1) & 7;
                        const int tsrc = (c == 7) ? ((t + 1) & 127) : t;
                        STAGE_GI(tsrc, grp, g * 2 + kh);
                    }
                    asm volatile("s_waitcnt vmcnt(10)" ::: "memory");
                }
            }
        }

        // ---- LN reduce across lc lanes + ct waves ----
#pragma unroll
        for (int m = 1; m < 16; m <<= 1)
#pragma unroll
            for (int r = 0; r < 4; ++r) {
                sacc[r] += __shfl_xor(sacc[r], m);
                qacc[r] += __shfl_xor(qacc[r], m);
            }
        if (lc == 0) {
#pragma unroll
            for (int r = 0; r < 4; ++r) {
                lnS[rt * 16 + kg * 4 + r][ct] = sacc[r];
                lnQ[rt * 16 + kg * 4 + r][ct] = qacc[r];
            }
        }
        asm volatile("s_waitcnt lgkmcnt(0)" ::: "memory");
        __builtin_amdgcn_s_barrier();
        __builtin_amdgcn_sched_barrier(0);

        // ---- LN finalize + out stores (+hT at last step) ----
#pragma unroll
        for (int r = 0; r < 4; ++r) {
            const int row = rt * 16 + kg * 4 + r;
            f32x4 vs = *(const f32x4*)&lnS[row][0];
            f32x4 vq = *(const f32x4*)&lnQ[row][0];
            const float s = vs[0] + vs[1] + vs[2] + vs[3];
            const float q = vq[0] + vq[1] + vq[2] + vq[3];
            const float mu   = s * (1.f / 512.f);
            const float var  = q * (1.f / 512.f) - mu * mu;
            const float rstd = rsqrtf(var + 1e-5f);
            float* orow = out + ((size_t)t * 512 + n0 + row) * 512;
#pragma unroll
            for (int c = 0; c < 8; ++c) {
                const int col = c * 64 + ct * 16 + lc;
                float o = (hreg[c][r] - mu) * rstd * gr[col] + br[col];
                __builtin_nontemporal_store(o, orow + col);
            }
            if (t == 127) {
#pragma unroll
                for (int c = 0; c < 8; ++c) {
                    const int col = c * 64 + ct * 16 + lc;
                    hT[(size_t)(n0 + row) * 512 + col] = hreg[c][r];
                }
            }
        }
    }
#undef STAGE_W
#undef STAGE_GI
}

// ---------------- launch ----------------
extern "C" void kernel_launch(void* const* d_in, const int* in_sizes, int n_in,
                              void* d_out, int out_size, void* d_ws, size_t ws_size,
                              hipStream_t stream) {
    const float* obs      = (const float*)d_in[0];
    const float* hx       = (const float*)d_in[1];
    const float* on_reset = (const float*)d_in[2];
    const float* W1  = (const float*)d_in[3];
    const float* b1  = (const float*)d_in[4];
    const float* g1  = (const float*)d_in[5];
    const float* be1 = (const float*)d_in[6];
    const float* W2  = (const float*)d_in[7];
    const float* b2  = (const float*)d_in[8];
    const float* g2  = (const float*)d_in[9];
    const float* be2 = (const float*)d_in[10];
    const float* Wih = (const float*)d_in[11];
    const float* Whh = (const float*)d_in[12];
    const float* bih = (const float*)d_in[13];
    const float* bhh = (const float*)d_in[14];
    const float* gr  = (const float*)d_in[15];
    const float* br  = (const float*)d_in[16];

    // workspace layout (bytes) — proven 272,236,544 footprint
    char* ws = (char*)d_ws;
    bf16* W1b  = (bf16*)(ws + 0);                    //   131072
    bf16* W2b  = (bf16*)(ws + 131072);               //   524288
    bf16* Wihb = (bf16*)(ws + 655360);               //  1572864
    bf16* Whhb = (bf16*)(ws + 2228224);              //  1572864
    bf16* Y    = (bf16*)(ws + 3801088);              // 67108864  (post-LN acts)
    bf16* GI   = (bf16*)(ws + 3801088 + 67108864);   // 201326592 (gi)
    bf16* X1   = GI;                                 // alias: pre-LN acts (dead before GI)
    bf16* OBSB = (bf16*)((char*)GI + 67108864);      // alias: obs bf16 (dead before GI)

    // conversions
    f32_to_bf16_vec<<<(1048576 + 255) / 256, 256, 0, stream>>>(obs, OBSB, 1048576);
    f32_to_bf16_vec<<<(8192 + 255) / 256,  256, 0, stream>>>(W1,  W1b,  8192);
    f32_to_bf16_vec<<<(32768 + 255) / 256, 256, 0, stream>>>(W2,  W2b,  32768);
    f32_to_bf16_vec<<<(98304 + 255) / 256, 256, 0, stream>>>(Wih, Wihb, 98304);
    f32_to_bf16_vec<<<(98304 + 255) / 256, 256, 0, stream>>>(Whh, Whhb, 98304);

    // MLP + gi
    gemm_xwt<128, true><<<dim3(512, 4), 256, 0, stream>>>(OBSB, W1b, b1, X1, 512);
    ln_rows512<<<16384, 256, 0, stream>>>(X1, Y, g1, be1);
    gemm_xwt<512, true><<<dim3(512, 4), 256, 0, stream>>>(Y, W2b, b2, X1, 512);
    ln_rows512<<<16384, 256, 0, stream>>>(X1, Y, g2, be2);
    gemm_xwt<512, false><<<dim3(512, 12), 256, 0, stream>>>(Y, Wihb, bih, GI, 1536);

    // GRU scan (DMA-pipelined Whh, fused final LN) + hT
    float* out_p = (float*)d_out;
    float* hT_p  = out_p + (size_t)65536 * 512;
    gru_scan8<<<16, 512, 0, stream>>>(GI, on_reset, hx, Whhb, bhh, gr, br, out_p, hT_p);
}

// Round 9
// 6535.799 us; speedup vs baseline: 1.2733x; 1.2733x over previous
//
#include <hip/hip_runtime.h>
#include <hip/hip_bf16.h>

using bf16 = __hip_bfloat16;
typedef __attribute__((ext_vector_type(8))) short short8;
typedef __attribute__((ext_vector_type(4))) float f32x4;

static __device__ __forceinline__ float b2f(unsigned short s) {
    unsigned u = ((unsigned)s) << 16;
    return __builtin_bit_cast(float, u);
}
static __device__ __forceinline__ short f2b(float f) {
    __hip_bfloat16 h = __float2bfloat16(f);
    return __builtin_bit_cast(short, h);
}
static __device__ __forceinline__ void load_lds16(const void* g, void* l) {
    __builtin_amdgcn_global_load_lds(
        (const __attribute__((address_space(1))) void*)g,
        (__attribute__((address_space(3))) void*)l, 16, 0, 0);
}

// ---------------- f32 -> bf16 conversion (8 elems/thread) ----------------
__global__ void f32_to_bf16_vec(const float* __restrict__ in, bf16* __restrict__ out, int n8) {
    int i = blockIdx.x * blockDim.x + threadIdx.x;
    if (i >= n8) return;
    const f32x4* p = (const f32x4*)(in + (size_t)i * 8);
    f32x4 a = p[0], b = p[1];
    short8 o;
    o[0] = f2b(a[0]); o[1] = f2b(a[1]); o[2] = f2b(a[2]); o[3] = f2b(a[3]);
    o[4] = f2b(b[0]); o[5] = f2b(b[1]); o[6] = f2b(b[2]); o[7] = f2b(b[3]);
    *(short8*)(out + (size_t)i * 8) = o;
}

// ---------------- GEMM: C = act(X @ W^T + bias), bf16 in/out ----------------
template<int K, bool RELU>
__global__ __launch_bounds__(256) void gemm_xwt(
    const bf16* __restrict__ X, const bf16* __restrict__ W,
    const float* __restrict__ bias, bf16* __restrict__ C, int Nout)
{
    __shared__ bf16 As[128][40];
    __shared__ bf16 Bs[128][40];
    const int tid  = threadIdx.x;
    const int wave = tid >> 6, lane = tid & 63;
    const int wr = wave >> 1, wc = wave & 1;
    const long Mbase = (long)blockIdx.x * 128;
    const int  Nbase = blockIdx.y * 128;
    const int kg = (lane >> 4) * 8;

    f32x4 acc[4][4];
#pragma unroll
    for (int i = 0; i < 4; ++i)
#pragma unroll
        for (int j = 0; j < 4; ++j) acc[i][j] = (f32x4){0.f, 0.f, 0.f, 0.f};

    for (int kb = 0; kb < K / 32; ++kb) {
        __syncthreads();
#pragma unroll
        for (int q = 0; q < 2; ++q) {
            int idx = q * 256 + tid;
            int row = idx >> 2, kp = (idx & 3) * 8;
            *(short8*)&As[row][kp] = *(const short8*)&X[(Mbase + row) * K + kb * 32 + kp];
            *(short8*)&Bs[row][kp] = *(const short8*)&W[(long)(Nbase + row) * K + kb * 32 + kp];
        }
        __syncthreads();
        short8 a[4], b[4];
#pragma unroll
        for (int mt = 0; mt < 4; ++mt)
            a[mt] = *(const short8*)&As[wr * 64 + mt * 16 + (lane & 15)][kg];
#pragma unroll
        for (int nt = 0; nt < 4; ++nt)
            b[nt] = *(const short8*)&Bs[wc * 64 + nt * 16 + (lane & 15)][kg];
#pragma unroll
        for (int mt = 0; mt < 4; ++mt)
#pragma unroll
            for (int nt = 0; nt < 4; ++nt)
                acc[mt][nt] = __builtin_amdgcn_mfma_f32_16x16x32_bf16(a[mt], b[nt], acc[mt][nt], 0, 0, 0);
    }

#pragma unroll
    for (int mt = 0; mt < 4; ++mt) {
        int row0 = wr * 64 + mt * 16 + (lane >> 4) * 4;
#pragma unroll
        for (int nt = 0; nt < 4; ++nt) {
            int col = Nbase + wc * 64 + nt * 16 + (lane & 15);
            float bv = bias[col];
#pragma unroll
            for (int r = 0; r < 4; ++r) {
                float v = acc[mt][nt][r] + bv;
                if (RELU) v = fmaxf(v, 0.f);
                C[(Mbase + row0 + r) * (long)Nout + col] = __float2bfloat16(v);
            }
        }
    }
}

// ---------------- LayerNorm rows of 512, bf16 -> bf16 ----------------
__global__ __launch_bounds__(256) void ln_rows512(
    const bf16* __restrict__ in, bf16* __restrict__ out,
    const float* __restrict__ g, const float* __restrict__ be)
{
    const int lane = threadIdx.x & 63;
    const long row = (long)blockIdx.x * 4 + (threadIdx.x >> 6);
    const bf16* rp = in + row * 512;
    short8 v = *(const short8*)&rp[lane * 8];
    float x[8]; float s = 0.f, sq = 0.f;
#pragma unroll
    for (int j = 0; j < 8; ++j) { x[j] = b2f((unsigned short)v[j]); s += x[j]; sq += x[j] * x[j]; }
#pragma unroll
    for (int m = 1; m < 64; m <<= 1) { s += __shfl_xor(s, m); sq += __shfl_xor(sq, m); }
    float mu   = s * (1.f / 512.f);
    float var  = sq * (1.f / 512.f) - mu * mu;
    float rstd = rsqrtf(var + 1e-5f);
    short8 o;
#pragma unroll
    for (int j = 0; j < 8; ++j) {
        int c = lane * 8 + j;
        o[j] = f2b((x[j] - mu) * rstd * g[c] + be[c]);
    }
    *(short8*)(out + row * 512 + lane * 8) = o;
}

// ---------------- final LayerNorm rows of 512, bf16 -> f32 ----------------
__global__ __launch_bounds__(256) void ln_rows512_f32out(
    const bf16* __restrict__ in, float* __restrict__ out,
    const float* __restrict__ g, const float* __restrict__ be)
{
    const int lane = threadIdx.x & 63;
    const long row = (long)blockIdx.x * 4 + (threadIdx.x >> 6);
    const bf16* rp = in + row * 512;
    short8 v = *(const short8*)&rp[lane * 8];
    float x[8]; float s = 0.f, sq = 0.f;
#pragma unroll
    for (int j = 0; j < 8; ++j) { x[j] = b2f((unsigned short)v[j]); s += x[j]; sq += x[j] * x[j]; }
#pragma unroll
    for (int m = 1; m < 64; m <<= 1) { s += __shfl_xor(s, m); sq += __shfl_xor(sq, m); }
    float mu   = s * (1.f / 512.f);
    float var  = sq * (1.f / 512.f) - mu * mu;
    float rstd = rsqrtf(var + 1e-5f);
    float* op = out + row * 512 + lane * 8;
#pragma unroll
    for (int c4 = 0; c4 < 2; ++c4) {
        f32x4 o;
#pragma unroll
        for (int j = 0; j < 4; ++j) {
            int c = lane * 8 + c4 * 4 + j;
            o[j] = (x[c4 * 4 + j] - mu) * rstd * g[c] + be[c];
        }
        *(f32x4*)(op + c4 * 4) = o;
    }
}

// ---------------- GRU scan v9: column-split, Whh LDS-resident, RMW-poll barrier ----
// 256 blocks x 256 threads, 1 block/CU (131KB LDS), all co-resident.
// Group = 16 blocks sharing (bid&7, (bid>>3)&1) -> same batch-chunk of 32 rows,
// likely same XCD. Block owns 32 h-cols: Whh slice (96x512 bf16 = 98KB) lives in
// LDS for the whole scan. Per step: DMA own 32 rows of pre-masked bf16 h (32KB),
// 48 MFMA/wave, gates in-register, write own 32x32 patch to the other h buffer,
// 16-block barrier via release-add + ACQUIRE-RMW poll (coherence-point safe).
__global__ __launch_bounds__(256, 1) void gru_scan9(
    const bf16* __restrict__ gi, const float* __restrict__ on_reset,
    const float* __restrict__ hx, const bf16* __restrict__ Whh,
    const float* __restrict__ bhh,
    bf16* __restrict__ hA, bf16* __restrict__ hB,
    bf16* __restrict__ h_all, float* __restrict__ hT,
    unsigned* __restrict__ bar)
{
    __shared__ bf16 Wl[96 * 512];   // 98304 B, row stride 1024B, XOR-swizzled storage
    __shared__ bf16 hS[32 * 512];   // 32768 B, row stride 1024B, XOR-swizzled storage

    const int tid = threadIdx.x;
    const int bid = blockIdx.x;
    const int xcd = bid & 7, sub = bid >> 3;      // sub 0..31
    const int g   = xcd * 2 + (sub & 1);          // batch-chunk 0..15 (16 blocks, same XCD likely)
    const int cc  = sub >> 1;                     // col-chunk 0..15
    const int n0 = g * 32, c0 = cc * 32;
    unsigned* cnt = bar + g * 64;                 // 256B apart

    const int w = tid >> 6, lane = tid & 63;
    const int lc = lane & 15, kg = lane >> 4;
    const int rt = w >> 1, hh = w & 1;            // row-tile (2), col-half (2)
    const int cg = c0 + hh * 16 + lc;             // owned global h-col

    char* Wlb = (char*)Wl;
    char* hSb = (char*)hS;

#define GROUP_BARRIER(n) do {                                                          \
        __threadfence();                                                               \
        __syncthreads();                                                               \
        if (tid == 0) {                                                                \
            __hip_atomic_fetch_add(cnt, 1u, __ATOMIC_RELEASE, __HIP_MEMORY_SCOPE_AGENT); \
            while (__hip_atomic_fetch_add(cnt, 0u, __ATOMIC_ACQUIRE,                   \
                                          __HIP_MEMORY_SCOPE_AGENT) < 16u * (unsigned)(n)) {} \
        }                                                                              \
        __syncthreads();                                                               \
        __threadfence();                                                               \
    } while (0)

    // ---- Wl: DMA the 96-row Whh slice once (src pre-swizzled, dest linear) ----
    {
        const char* Wb = (const char*)Whh;
#pragma unroll
        for (int i2 = 0; i2 < 24; ++i2) {
            const int i = i2 * 256 + tid;
            const int row = i >> 6, l16 = i & 63;   // one row per wave-instruction
            const int gRow = (row >> 5) * 512 + c0 + (row & 31);
            load_lds16(Wb + (size_t)gRow * 1024 + ((l16 * 16) ^ ((row & 7) << 4)),
                       Wlb + i * 16);
        }
    }

    // ---- hoisted per-lane constants ----
    const float bhr = bhh[cg], bhz = bhh[512 + cg], bhn = bhh[1024 + cg];

    // ---- h0 init: own 32x32 patch (f32 master in regs, pre-masked bf16 to hA) ----
    float hreg[4];
#pragma unroll
    for (int r = 0; r < 4; ++r) {
        const int row = rt * 16 + kg * 4 + r;
        const float m0 = on_reset[n0 + row];
        float v = hx[(size_t)(n0 + row) * 512 + cg];
        hreg[r] = v;
        hA[(size_t)(n0 + row) * 512 + cg] = __float2bfloat16(v * m0);
    }
    asm volatile("s_waitcnt vmcnt(0)" ::: "memory");   // Wl DMA + hA stores drained
    GROUP_BARRIER(1);

#pragma unroll 1
    for (int t = 0; t < 128; ++t) {
        const bf16* hcur = (t & 1) ? hB : hA;
        bf16*       hnxt = (t & 1) ? hA : hB;

        // ---- stage own 32 rows of hcur into hS (DMA, src pre-swizzled) ----
        {
            const char* hbp = (const char*)hcur + (size_t)n0 * 1024;
#pragma unroll
            for (int i2 = 0; i2 < 8; ++i2) {
                const int i = i2 * 256 + tid;
                const int row = i >> 6, l16 = i & 63;
                load_lds16(hbp + row * 1024 + ((l16 * 16) ^ ((row & 7) << 4)),
                           hSb + i * 16);
            }
        }

        // ---- gi + masks issued early (in flight during DMA wait) ----
        float irv[4], izv[4], inv[4], mcur[4], mnx[4];
#pragma unroll
        for (int r = 0; r < 4; ++r) {
            const int row = rt * 16 + kg * 4 + r;
            const unsigned short* gp =
                (const unsigned short*)gi + ((size_t)t * 512 + n0 + row) * 1536;
            irv[r] = b2f(__builtin_nontemporal_load(gp + cg));
            izv[r] = b2f(__builtin_nontemporal_load(gp + 512 + cg));
            inv[r] = b2f(__builtin_nontemporal_load(gp + 1024 + cg));
            mcur[r] = on_reset[(size_t)t * 512 + n0 + row];
            mnx[r]  = (t < 127) ? on_reset[(size_t)(t + 1) * 512 + n0 + row] : 1.f;
        }

        asm volatile("s_waitcnt vmcnt(0)" ::: "memory");
        __syncthreads();   // hS ready for all waves

        // ---- A-frags from hS ----
        short8 aF[16];
        const int arow = rt * 16 + lc;
        const int asw = (arow & 7) << 4;
#pragma unroll
        for (int kc = 0; kc < 16; ++kc)
            aF[kc] = *(const short8*)(hSb + arow * 1024 + ((kc * 64 + kg * 16) ^ asw));

        // ---- MFMA: 3 gates x 16 k-slices (B from LDS-resident Wl) ----
        f32x4 acc[3];
#pragma unroll
        for (int gt = 0; gt < 3; ++gt) acc[gt] = (f32x4){0.f, 0.f, 0.f, 0.f};
#pragma unroll
        for (int gt = 0; gt < 3; ++gt) {
            const int wrow = gt * 32 + hh * 16 + lc;
            const int wsw = (wrow & 7) << 4;
#pragma unroll
            for (int kc = 0; kc < 16; ++kc) {
                short8 bq = *(const short8*)(Wlb + wrow * 1024 + ((kc * 64 + kg * 16) ^ wsw));
                acc[gt] = __builtin_amdgcn_mfma_f32_16x16x32_bf16(aF[kc], bq, acc[gt], 0, 0, 0);
            }
        }

        // ---- gates + h update + stores ----
#pragma unroll
        for (int r = 0; r < 4; ++r) {
            const int row = rt * 16 + kg * 4 + r;
            const float hr = acc[0][r] + bhr;
            const float hz = acc[1][r] + bhz;
            const float hn = acc[2][r] + bhn;
            const float rg = 1.f / (1.f + __expf(-(irv[r] + hr)));
            const float zg = 1.f / (1.f + __expf(-(izv[r] + hz)));
            const float e2 = __expf(2.f * (inv[r] + rg * hn));
            const float ng = 1.f - 2.f / (e2 + 1.f);   // tanh
            const float hv = (1.f - zg) * ng + zg * (hreg[r] * mcur[r]);
            hreg[r] = hv;
            h_all[((size_t)t * 512 + n0 + row) * 512 + cg] = __float2bfloat16(hv);
            if (t < 127)
                hnxt[(size_t)(n0 + row) * 512 + cg] = __float2bfloat16(hv * mnx[r]);
        }

        GROUP_BARRIER(t + 2);
    }

    // ---- hT = h_127 (unmasked, f32) ----
#pragma unroll
    for (int r = 0; r < 4; ++r) {
        const int row = rt * 16 + kg * 4 + r;
        hT[(size_t)(n0 + row) * 512 + cg] = hreg[r];
    }
#undef GROUP_BARRIER
}

// ---------------- launch ----------------
extern "C" void kernel_launch(void* const* d_in, const int* in_sizes, int n_in,
                              void* d_out, int out_size, void* d_ws, size_t ws_size,
                              hipStream_t stream) {
    const float* obs      = (const float*)d_in[0];
    const float* hx       = (const float*)d_in[1];
    const float* on_reset = (const float*)d_in[2];
    const float* W1  = (const float*)d_in[3];
    const float* b1  = (const float*)d_in[4];
    const float* g1  = (const float*)d_in[5];
    const float* be1 = (const float*)d_in[6];
    const float* W2  = (const float*)d_in[7];
    const float* b2  = (const float*)d_in[8];
    const float* g2  = (const float*)d_in[9];
    const float* be2 = (const float*)d_in[10];
    const float* Wih = (const float*)d_in[11];
    const float* Whh = (const float*)d_in[12];
    const float* bih = (const float*)d_in[13];
    const float* bhh = (const float*)d_in[14];
    const float* gr  = (const float*)d_in[15];
    const float* br  = (const float*)d_in[16];

    // workspace layout (bytes) — proven 272,236,544 footprint
    // Scan-time liveness: W1b/W2b/Wihb dead -> reuse for hA/hB/bar. Whhb stays live.
    char* ws = (char*)d_ws;
    bf16* W1b  = (bf16*)(ws + 0);                    //   131072 (dead after GEMM1)
    bf16* W2b  = (bf16*)(ws + 131072);               //   524288 (dead after GEMM2)
    bf16* Wihb = (bf16*)(ws + 655360);               //  1572864 (dead after GEMM3)
    bf16* Whhb = (bf16*)(ws + 2228224);              //  1572864 (LIVE through scan)
    bf16* Y    = (bf16*)(ws + 3801088);              // 67108864 (post-LN acts; later h_all)
    bf16* GI   = (bf16*)(ws + 3801088 + 67108864);   // 201326592 (gi)
    bf16* X1   = GI;                                 // alias: pre-LN acts (dead before GI)
    bf16* OBSB = (bf16*)((char*)GI + 67108864);      // alias: obs bf16 (dead before GI)
    bf16* hAb  = (bf16*)(ws + 0);                    //   524288 over dead W1b+W2b
    bf16* hBb  = (bf16*)(ws + 655360);               //   524288 over dead Wihb head
    unsigned* bar = (unsigned*)(ws + 1179648);       //     4096 (inside dead Wihb)
    bf16* h_all = Y;                                 // alias: Y dead after gi GEMM

    // conversions
    f32_to_bf16_vec<<<(1048576 + 255) / 256, 256, 0, stream>>>(obs, OBSB, 1048576);
    f32_to_bf16_vec<<<(8192 + 255) / 256,  256, 0, stream>>>(W1,  W1b,  8192);
    f32_to_bf16_vec<<<(32768 + 255) / 256, 256, 0, stream>>>(W2,  W2b,  32768);
    f32_to_bf16_vec<<<(98304 + 255) / 256, 256, 0, stream>>>(Wih, Wihb, 98304);
    f32_to_bf16_vec<<<(98304 + 255) / 256, 256, 0, stream>>>(Whh, Whhb, 98304);

    // MLP + gi
    gemm_xwt<128, true><<<dim3(512, 4), 256, 0, stream>>>(OBSB, W1b, b1, X1, 512);
    ln_rows512<<<16384, 256, 0, stream>>>(X1, Y, g1, be1);
    gemm_xwt<512, true><<<dim3(512, 4), 256, 0, stream>>>(Y, W2b, b2, X1, 512);
    ln_rows512<<<16384, 256, 0, stream>>>(X1, Y, g2, be2);
    gemm_xwt<512, false><<<dim3(512, 12), 256, 0, stream>>>(Y, Wihb, bih, GI, 1536);

    // scan (column-split, LDS-resident Whh, RMW-poll group barriers)
    hipMemsetAsync(bar, 0, 4096, stream);
    float* out_p = (float*)d_out;
    float* hT_p  = out_p + (size_t)65536 * 512;
    gru_scan9<<<256, 256, 0, stream>>>(GI, on_reset, hx, Whhb, bhh,
                                       hAb, hBb, h_all, hT_p, bar);

    // final LN: bf16 h_all -> f32 out
    ln_rows512_f32out<<<16384, 256, 0, stream>>>(h_all, out_p, gr, br);
}

// Round 10
// 1997.884 us; speedup vs baseline: 4.1653x; 3.2714x over previous
//
#include <hip/hip_runtime.h>
#include <hip/hip_bf16.h>

using bf16 = __hip_bfloat16;
typedef __attribute__((ext_vector_type(8))) short short8;
typedef __attribute__((ext_vector_type(4))) float f32x4;

static __device__ __forceinline__ float b2f(unsigned short s) {
    unsigned u = ((unsigned)s) << 16;
    return __builtin_bit_cast(float, u);
}
static __device__ __forceinline__ short f2b(float f) {
    __hip_bfloat16 h = __float2bfloat16(f);
    return __builtin_bit_cast(short, h);
}
static __device__ __forceinline__ void load_lds16(const void* g, void* l) {
    __builtin_amdgcn_global_load_lds(
        (const __attribute__((address_space(1))) void*)g,
        (__attribute__((address_space(3))) void*)l, 16, 0, 0);
}

// ---------------- f32 -> bf16 conversion (8 elems/thread) ----------------
__global__ void f32_to_bf16_vec(const float* __restrict__ in, bf16* __restrict__ out, int n8) {
    int i = blockIdx.x * blockDim.x + threadIdx.x;
    if (i >= n8) return;
    const f32x4* p = (const f32x4*)(in + (size_t)i * 8);
    f32x4 a = p[0], b = p[1];
    short8 o;
    o[0] = f2b(a[0]); o[1] = f2b(a[1]); o[2] = f2b(a[2]); o[3] = f2b(a[3]);
    o[4] = f2b(b[0]); o[5] = f2b(b[1]); o[6] = f2b(b[2]); o[7] = f2b(b[3]);
    *(short8*)(out + (size_t)i * 8) = o;
}

// ---------------- GEMM: C = act(X @ W^T + bias), bf16 in/out ----------------
template<int K, bool RELU>
__global__ __launch_bounds__(256) void gemm_xwt(
    const bf16* __restrict__ X, const bf16* __restrict__ W,
    const float* __restrict__ bias, bf16* __restrict__ C, int Nout)
{
    __shared__ bf16 As[128][40];
    __shared__ bf16 Bs[128][40];
    const int tid  = threadIdx.x;
    const int wave = tid >> 6, lane = tid & 63;
    const int wr = wave >> 1, wc = wave & 1;
    const long Mbase = (long)blockIdx.x * 128;
    const int  Nbase = blockIdx.y * 128;
    const int kg = (lane >> 4) * 8;

    f32x4 acc[4][4];
#pragma unroll
    for (int i = 0; i < 4; ++i)
#pragma unroll
        for (int j = 0; j < 4; ++j) acc[i][j] = (f32x4){0.f, 0.f, 0.f, 0.f};

    for (int kb = 0; kb < K / 32; ++kb) {
        __syncthreads();
#pragma unroll
        for (int q = 0; q < 2; ++q) {
            int idx = q * 256 + tid;
            int row = idx >> 2, kp = (idx & 3) * 8;
            *(short8*)&As[row][kp] = *(const short8*)&X[(Mbase + row) * K + kb * 32 + kp];
            *(short8*)&Bs[row][kp] = *(const short8*)&W[(long)(Nbase + row) * K + kb * 32 + kp];
        }
        __syncthreads();
        short8 a[4], b[4];
#pragma unroll
        for (int mt = 0; mt < 4; ++mt)
            a[mt] = *(const short8*)&As[wr * 64 + mt * 16 + (lane & 15)][kg];
#pragma unroll
        for (int nt = 0; nt < 4; ++nt)
            b[nt] = *(const short8*)&Bs[wc * 64 + nt * 16 + (lane & 15)][kg];
#pragma unroll
        for (int mt = 0; mt < 4; ++mt)
#pragma unroll
            for (int nt = 0; nt < 4; ++nt)
                acc[mt][nt] = __builtin_amdgcn_mfma_f32_16x16x32_bf16(a[mt], b[nt], acc[mt][nt], 0, 0, 0);
    }

#pragma unroll
    for (int mt = 0; mt < 4; ++mt) {
        int row0 = wr * 64 + mt * 16 + (lane >> 4) * 4;
#pragma unroll
        for (int nt = 0; nt < 4; ++nt) {
            int col = Nbase + wc * 64 + nt * 16 + (lane & 15);
            float bv = bias[col];
#pragma unroll
            for (int r = 0; r < 4; ++r) {
                float v = acc[mt][nt][r] + bv;
                if (RELU) v = fmaxf(v, 0.f);
                C[(Mbase + row0 + r) * (long)Nout + col] = __float2bfloat16(v);
            }
        }
    }
}

// ---------------- LayerNorm rows of 512, bf16 -> bf16 ----------------
__global__ __launch_bounds__(256) void ln_rows512(
    const bf16* __restrict__ in, bf16* __restrict__ out,
    const float* __restrict__ g, const float* __restrict__ be)
{
    const int lane = threadIdx.x & 63;
    const long row = (long)blockIdx.x * 4 + (threadIdx.x >> 6);
    const bf16* rp = in + row * 512;
    short8 v = *(const short8*)&rp[lane * 8];
    float x[8]; float s = 0.f, sq = 0.f;
#pragma unroll
    for (int j = 0; j < 8; ++j) { x[j] = b2f((unsigned short)v[j]); s += x[j]; sq += x[j] * x[j]; }
#pragma unroll
    for (int m = 1; m < 64; m <<= 1) { s += __shfl_xor(s, m); sq += __shfl_xor(sq, m); }
    float mu   = s * (1.f / 512.f);
    float var  = sq * (1.f / 512.f) - mu * mu;
    float rstd = rsqrtf(var + 1e-5f);
    short8 o;
#pragma unroll
    for (int j = 0; j < 8; ++j) {
        int c = lane * 8 + j;
        o[j] = f2b((x[j] - mu) * rstd * g[c] + be[c]);
    }
    *(short8*)(out + row * 512 + lane * 8) = o;
}

// ---------------- final LayerNorm rows of 512, bf16 -> f32 ----------------
__global__ __launch_bounds__(256) void ln_rows512_f32out(
    const bf16* __restrict__ in, float* __restrict__ out,
    const float* __restrict__ g, const float* __restrict__ be)
{
    const int lane = threadIdx.x & 63;
    const long row = (long)blockIdx.x * 4 + (threadIdx.x >> 6);
    const bf16* rp = in + row * 512;
    short8 v = *(const short8*)&rp[lane * 8];
    float x[8]; float s = 0.f, sq = 0.f;
#pragma unroll
    for (int j = 0; j < 8; ++j) { x[j] = b2f((unsigned short)v[j]); s += x[j]; sq += x[j] * x[j]; }
#pragma unroll
    for (int m = 1; m < 64; m <<= 1) { s += __shfl_xor(s, m); sq += __shfl_xor(sq, m); }
    float mu   = s * (1.f / 512.f);
    float var  = sq * (1.f / 512.f) - mu * mu;
    float rstd = rsqrtf(var + 1e-5f);
    float* op = out + row * 512 + lane * 8;
#pragma unroll
    for (int c4 = 0; c4 < 2; ++c4) {
        f32x4 o;
#pragma unroll
        for (int j = 0; j < 4; ++j) {
            int c = lane * 8 + c4 * 4 + j;
            o[j] = (x[c4 * 4 + j] - mu) * rstd * g[c] + be[c];
        }
        *(f32x4*)(op + c4 * 4) = o;
    }
}

// ---------------- GRU scan v10: column-split + distributed flag barrier ----------------
// 256 blocks x 256 threads, 1 block/CU (131KB LDS), all co-resident.
// Group = 16 blocks sharing a 32-row batch-chunk (same XCD by bid&7 heuristic).
// Block owns 32 h-cols; Whh slice (96x512 bf16 = 98KB) LDS-resident for the scan.
// Sync: per-block monotonic step-flags on private 128B lines. End of step t:
// __syncthreads (drains stores) then ONE release atomic store flag=t+2.
// Start of step t: wave0 lanes 0-15 ACQUIRE-load the 16 flags (read-only, no
// ownership bounce), ballot until all >= t+1. Other waves prefetch gi meanwhile.
__global__ __launch_bounds__(256, 1) void gru_scan10(
    const bf16* __restrict__ gi, const float* __restrict__ on_reset,
    const float* __restrict__ hx, const bf16* __restrict__ Whh,
    const float* __restrict__ bhh,
    bf16* __restrict__ hA, bf16* __restrict__ hB,
    bf16* __restrict__ h_all, float* __restrict__ hT,
    unsigned* __restrict__ bar)
{
    __shared__ bf16 Wl[96 * 512];   // 98304 B, row stride 1024B, XOR-swizzled storage
    __shared__ bf16 hS[32 * 512];   // 32768 B, row stride 1024B, XOR-swizzled storage

    const int tid = threadIdx.x;
    const int bid = blockIdx.x;
    const int xcd = bid & 7, sub = bid >> 3;      // sub 0..31
    const int g   = xcd * 2 + (sub & 1);          // batch-chunk 0..15 (16 blocks, same XCD likely)
    const int cc  = sub >> 1;                     // col-chunk 0..15
    const int n0 = g * 32, c0 = cc * 32;
    unsigned* gflags = bar + g * 512;             // 16 flags x 32-u32 (128B) stride
    unsigned* myflag = gflags + cc * 32;

    const int w = tid >> 6, lane = tid & 63;
    const int lc = lane & 15, kg = lane >> 4;
    const int rt = w >> 1, hh = w & 1;            // row-tile (2), col-half (2)
    const int cg = c0 + hh * 16 + lc;             // owned global h-col

    char* Wlb = (char*)Wl;
    char* hSb = (char*)hS;

    // ---- Wl: DMA the 96-row Whh slice once (src pre-swizzled, dest linear) ----
    {
        const char* Wb = (const char*)Whh;
#pragma unroll
        for (int i2 = 0; i2 < 24; ++i2) {
            const int i = i2 * 256 + tid;
            const int row = i >> 6, l16 = i & 63;   // one row per wave-instruction
            const int gRow = (row >> 5) * 512 + c0 + (row & 31);
            load_lds16(Wb + (size_t)gRow * 1024 + ((l16 * 16) ^ ((row & 7) << 4)),
                       Wlb + i * 16);
        }
    }

    // ---- hoisted per-lane constants ----
    const float bhr = bhh[cg], bhz = bhh[512 + cg], bhn = bhh[1024 + cg];

    // ---- h0 init: own 32x32 patch (f32 master in regs, pre-masked bf16 to hA) ----
    float hreg[4];
#pragma unroll
    for (int r = 0; r < 4; ++r) {
        const int row = rt * 16 + kg * 4 + r;
        const float m0 = on_reset[n0 + row];
        float v = hx[(size_t)(n0 + row) * 512 + cg];
        hreg[r] = v;
        hA[(size_t)(n0 + row) * 512 + cg] = __float2bfloat16(v * m0);
    }
    __syncthreads();   // drains all waves' stores (vmcnt0) + Wl DMA issued
    asm volatile("s_waitcnt vmcnt(0)" ::: "memory");
    if (tid == 0)
        __hip_atomic_store(myflag, 1u, __ATOMIC_RELEASE, __HIP_MEMORY_SCOPE_AGENT);

#pragma unroll 1
    for (int t = 0; t < 128; ++t) {
        const bf16* hcur = (t & 1) ? hB : hA;
        bf16*       hnxt = (t & 1) ? hA : hB;

        // ---- gi + masks issued early (independent of h; overlaps the poll) ----
        float irv[4], izv[4], inv[4], mcur[4], mnx[4];
#pragma unroll
        for (int r = 0; r < 4; ++r) {
            const int row = rt * 16 + kg * 4 + r;
            const unsigned short* gp =
                (const unsigned short*)gi + ((size_t)t * 512 + n0 + row) * 1536;
            irv[r] = b2f(__builtin_nontemporal_load(gp + cg));
            izv[r] = b2f(__builtin_nontemporal_load(gp + 512 + cg));
            inv[r] = b2f(__builtin_nontemporal_load(gp + 1024 + cg));
            mcur[r] = on_reset[(size_t)t * 512 + n0 + row];
            mnx[r]  = (t < 127) ? on_reset[(size_t)(t + 1) * 512 + n0 + row] : 1.f;
        }

        // ---- distributed-flag barrier: wait for all 16 flags >= t+1 ----
        if (w == 0) {
            const unsigned tgt = (unsigned)(t + 1);
            unsigned* fp = gflags + (lane & 15) * 32;
            for (;;) {
                unsigned v = (lane < 16)
                    ? __hip_atomic_load(fp, __ATOMIC_ACQUIRE, __HIP_MEMORY_SCOPE_AGENT)
                    : tgt;
                if (__all(v >= tgt)) break;
                __builtin_amdgcn_s_sleep(2);
            }
        }
        __syncthreads();   // all waves held until h_t visible

        // ---- stage own 32 rows of h_t into hS (DMA, src pre-swizzled) ----
        {
            const char* hbp = (const char*)hcur + (size_t)n0 * 1024;
#pragma unroll
            for (int i2 = 0; i2 < 8; ++i2) {
                const int i = i2 * 256 + tid;
                const int row = i >> 6, l16 = i & 63;
                load_lds16(hbp + row * 1024 + ((l16 * 16) ^ ((row & 7) << 4)),
                           hSb + i * 16);
            }
        }
        asm volatile("s_waitcnt vmcnt(0)" ::: "memory");
        __syncthreads();   // hS ready for all waves

        // ---- A-frags from hS ----
        short8 aF[16];
        const int arow = rt * 16 + lc;
        const int asw = (arow & 7) << 4;
#pragma unroll
        for (int kc = 0; kc < 16; ++kc)
            aF[kc] = *(const short8*)(hSb + arow * 1024 + ((kc * 64 + kg * 16) ^ asw));

        // ---- MFMA: 3 gates x 16 k-slices (B from LDS-resident Wl) ----
        f32x4 acc[3];
#pragma unroll
        for (int gt = 0; gt < 3; ++gt) acc[gt] = (f32x4){0.f, 0.f, 0.f, 0.f};
#pragma unroll
        for (int gt = 0; gt < 3; ++gt) {
            const int wrow = gt * 32 + hh * 16 + lc;
            const int wsw = (wrow & 7) << 4;
#pragma unroll
            for (int kc = 0; kc < 16; ++kc) {
                short8 bq = *(const short8*)(Wlb + wrow * 1024 + ((kc * 64 + kg * 16) ^ wsw));
                acc[gt] = __builtin_amdgcn_mfma_f32_16x16x32_bf16(aF[kc], bq, acc[gt], 0, 0, 0);
            }
        }

        // ---- gates + h update + stores ----
#pragma unroll
        for (int r = 0; r < 4; ++r) {
            const int row = rt * 16 + kg * 4 + r;
            const float hr = acc[0][r] + bhr;
            const float hz = acc[1][r] + bhz;
            const float hn = acc[2][r] + bhn;
            const float rg = 1.f / (1.f + __expf(-(irv[r] + hr)));
            const float zg = 1.f / (1.f + __expf(-(izv[r] + hz)));
            const float e2 = __expf(2.f * (inv[r] + rg * hn));
            const float ng = 1.f - 2.f / (e2 + 1.f);   // tanh
            const float hv = (1.f - zg) * ng + zg * (hreg[r] * mcur[r]);
            hreg[r] = hv;
            h_all[((size_t)t * 512 + n0 + row) * 512 + cg] = __float2bfloat16(hv);
            if (t < 127)
                hnxt[(size_t)(n0 + row) * 512 + cg] = __float2bfloat16(hv * mnx[r]);
        }

        if (t < 127) {
            __syncthreads();   // emits vmcnt(0): all waves' h stores complete
            if (tid == 0)
                __hip_atomic_store(myflag, (unsigned)(t + 2),
                                   __ATOMIC_RELEASE, __HIP_MEMORY_SCOPE_AGENT);
        }
    }

    // ---- hT = h_127 (unmasked, f32) ----
#pragma unroll
    for (int r = 0; r < 4; ++r) {
        const int row = rt * 16 + kg * 4 + r;
        hT[(size_t)(n0 + row) * 512 + cg] = hreg[r];
    }
}

// ---------------- launch ----------------
extern "C" void kernel_launch(void* const* d_in, const int* in_sizes, int n_in,
                              void* d_out, int out_size, void* d_ws, size_t ws_size,
                              hipStream_t stream) {
    const float* obs      = (const float*)d_in[0];
    const float* hx       = (const float*)d_in[1];
    const float* on_reset = (const float*)d_in[2];
    const float* W1  = (const float*)d_in[3];
    const float* b1  = (const float*)d_in[4];
    const float* g1  = (const float*)d_in[5];
    const float* be1 = (const float*)d_in[6];
    const float* W2  = (const float*)d_in[7];
    const float* b2  = (const float*)d_in[8];
    const float* g2  = (const float*)d_in[9];
    const float* be2 = (const float*)d_in[10];
    const float* Wih = (const float*)d_in[11];
    const float* Whh = (const float*)d_in[12];
    const float* bih = (const float*)d_in[13];
    const float* bhh = (const float*)d_in[14];
    const float* gr  = (const float*)d_in[15];
    const float* br  = (const float*)d_in[16];

    // workspace layout (bytes) — proven 272,236,544 footprint
    char* ws = (char*)d_ws;
    bf16* W1b  = (bf16*)(ws + 0);                    //   131072 (dead after GEMM1)
    bf16* W2b  = (bf16*)(ws + 131072);               //   524288 (dead after GEMM2)
    bf16* Wihb = (bf16*)(ws + 655360);               //  1572864 (dead after GEMM3)
    bf16* Whhb = (bf16*)(ws + 2228224);              //  1572864 (LIVE through scan)
    bf16* Y    = (bf16*)(ws + 3801088);              // 67108864 (post-LN acts; later h_all)
    bf16* GI   = (bf16*)(ws + 3801088 + 67108864);   // 201326592 (gi)
    bf16* X1   = GI;                                 // alias: pre-LN acts (dead before GI)
    bf16* OBSB = (bf16*)((char*)GI + 67108864);      // alias: obs bf16 (dead before GI)
    bf16* hAb  = (bf16*)(ws + 0);                    //   524288 over dead W1b+W2b
    bf16* hBb  = (bf16*)(ws + 655360);               //   524288 over dead Wihb head
    unsigned* bar = (unsigned*)(ws + 1179648);       //    32768 (16 groups x 16 flags x 128B)
    bf16* h_all = Y;                                 // alias: Y dead after gi GEMM

    // conversions
    f32_to_bf16_vec<<<(1048576 + 255) / 256, 256, 0, stream>>>(obs, OBSB, 1048576);
    f32_to_bf16_vec<<<(8192 + 255) / 256,  256, 0, stream>>>(W1,  W1b,  8192);
    f32_to_bf16_vec<<<(32768 + 255) / 256, 256, 0, stream>>>(W2,  W2b,  32768);
    f32_to_bf16_vec<<<(98304 + 255) / 256, 256, 0, stream>>>(Wih, Wihb, 98304);
    f32_to_bf16_vec<<<(98304 + 255) / 256, 256, 0, stream>>>(Whh, Whhb, 98304);

    // MLP + gi
    gemm_xwt<128, true><<<dim3(512, 4), 256, 0, stream>>>(OBSB, W1b, b1, X1, 512);
    ln_rows512<<<16384, 256, 0, stream>>>(X1, Y, g1, be1);
    gemm_xwt<512, true><<<dim3(512, 4), 256, 0, stream>>>(Y, W2b, b2, X1, 512);
    ln_rows512<<<16384, 256, 0, stream>>>(X1, Y, g2, be2);
    gemm_xwt<512, false><<<dim3(512, 12), 256, 0, stream>>>(Y, Wihb, bih, GI, 1536);

    // scan (column-split, LDS-resident Whh, distributed flag barrier)
    hipMemsetAsync(bar, 0, 32768, stream);
    float* out_p = (float*)d_out;
    float* hT_p  = out_p + (size_t)65536 * 512;
    gru_scan10<<<256, 256, 0, stream>>>(GI, on_reset, hx, Whhb, bhh,
                                        hAb, hBb, h_all, hT_p, bar);

    // final LN: bf16 h_all -> f32 out
    ln_rows512_f32out<<<16384, 256, 0, stream>>>(h_all, out_p, gr, br);
}